// Round 7
// baseline (614.436 us; speedup 1.0000x reference)
//
#include <hip/hip_runtime.h>
#include <cstdint>

typedef unsigned short u16;
typedef unsigned int   u32;
typedef unsigned long long u64;

#define G_ROWS 20000
#define G_PAD  20096      // 157 * 128
#define T_DIM  1536
#define D_DIM  512
#define B_DIM  256
#define TOPK   32
#define SIM_SCALE 0.04419417382415922f   // 1/sqrt(512), screening only
#define SQRT_D    22.62741699796952f     // f32(math.sqrt(512)) — np divides by this
#define BOUND_EPS 2.0e-4f                // screen-vs-np noise is ~5e-6; 40x margin

typedef __bf16 bf16x8 __attribute__((ext_vector_type(8)));
typedef float  f32x4  __attribute__((ext_vector_type(4)));

__device__ __forceinline__ u16 f2bf(float f) {
  u32 u = __float_as_uint(f);
  u += 0x7fffu + ((u >> 16) & 1u);   // RNE
  return (u16)(u >> 16);
}
__device__ __forceinline__ float bf2f(u16 h) {
  return __uint_as_float(((u32)h) << 16);
}
__device__ __forceinline__ u32 fkey(float v) {   // order-preserving f32 -> u32
  u32 b = __float_as_uint(v);
  return (b & 0x80000000u) ? ~b : (b | 0x80000000u);
}
__device__ __forceinline__ float funkey(u32 o) {
  u32 b = (o & 0x80000000u) ? (o & 0x7FFFFFFFu) : ~o;
  return __uint_as_float(b);
}

// ---------------- split-conversion: f32 -> (bf16 hi, bf16 lo) ----------------
__global__ __launch_bounds__(256) void conv_split(const float* __restrict__ src,
                                                  u16* __restrict__ hi, u16* __restrict__ lo,
                                                  int valid_rows)
{
  size_t i = ((size_t)blockIdx.x * 256 + threadIdx.x) * 4;
  int row = (int)(i >> 9);
  float4 a = make_float4(0.f, 0.f, 0.f, 0.f);
  if (row < valid_rows) a = *(const float4*)(src + i);
  float v[4] = {a.x, a.y, a.z, a.w};
  u16 h[4], l[4];
#pragma unroll
  for (int c = 0; c < 4; ++c) {
    h[c] = f2bf(v[c]);
    l[c] = f2bf(v[c] - bf2f(h[c]));
  }
  *(uint2*)(hi + i) = make_uint2((u32)h[0] | ((u32)h[1] << 16), (u32)h[2] | ((u32)h[3] << 16));
  *(uint2*)(lo + i) = make_uint2((u32)l[0] | ((u32)l[1] << 16), (u32)l[2] | ((u32)l[3] << 16));
}

// ---------------- tf_expr [B,T] -> tfT [T,B] ----------------
__global__ __launch_bounds__(256) void transpose_tf(const float* __restrict__ in, float* __restrict__ out)
{
  __shared__ float tile[32][33];
  int x = threadIdx.x, y = threadIdx.y;
  int bt = blockIdx.x * 32;
  int bb = blockIdx.y * 32;
#pragma unroll
  for (int i = 0; i < 32; i += 8) tile[y + i][x] = in[(size_t)(bb + y + i) * T_DIM + bt + x];
  __syncthreads();
#pragma unroll
  for (int i = 0; i < 32; i += 8) out[(size_t)(bt + y + i) * B_DIM + bb + x] = tile[x][y + i];
}

// ---------------- pack motif_mask [G,T] int32 -> bit array [G][48] u32 ----------------
__global__ __launch_bounds__(256) void pack_mask(const int* __restrict__ mask, u32* __restrict__ bits)
{
  const int lane = threadIdx.x & 63;
  const int wv   = threadIdx.x >> 6;
  const int g    = blockIdx.x * 4 + wv;
  const int* mrow = mask + (size_t)g * T_DIM;
  u64 mybits = 0;
#pragma unroll
  for (int j = 0; j < 24; ++j) {
    u64 b = __ballot(mrow[j * 64 + lane] != 0);   // bit l = element j*64+l
    if (lane == j) mybits = b;
  }
  if (lane < 24) *(u64*)(bits + (size_t)g * 48 + lane * 2) = mybits;
}

// ---------------- async global -> LDS, 16B/lane ----------------
__device__ __forceinline__ void gl16(const u16* g, u16* l) {
  __builtin_amdgcn_global_load_lds((__attribute__((address_space(1))) void*)(void*)g,
                                   (__attribute__((address_space(3))) void*)l, 16, 0, 0);
}

// ---------------- screening GEMM: C ~= (Ah+Al)(Bh+Bl)^T via 3 bf16 MFMA terms ----------------
__global__ __launch_bounds__(256) void gemm_split(const u16* __restrict__ Ah, const u16* __restrict__ Al,
                                                  const u16* __restrict__ Bh, const u16* __restrict__ Bl,
                                                  float* __restrict__ Sim)
{
  __shared__ u16 sm[16384];
  const int tid  = threadIdx.x;
  const int lane = tid & 63;
  const int wv   = tid >> 6;
  const int m0 = blockIdx.y * 128;
  const int n0 = blockIdx.x * 128;

  f32x4 zero4 = {0.f, 0.f, 0.f, 0.f};
  f32x4 acc[4][4];
#pragma unroll
  for (int i = 0; i < 4; ++i)
#pragma unroll
    for (int j = 0; j < 4; ++j) acc[i][j] = zero4;

  const int r0 = (wv << 4) + (lane >> 2);
  const int c0 = (lane & 3) << 3;
  const size_t aoff = (size_t)(m0 + r0) * 512 + c0;
  const size_t boff = (size_t)(n0 + r0) * 512 + c0;
  u16* lw = sm + (wv << 9);

  const int arow = ((wv >> 1) << 6) + (lane & 15);
  const int brow = ((wv & 1) << 6) + (lane & 15);
  const int kf   = (lane >> 4) << 3;

  for (int kt = 0; kt < 16; ++kt) {
    const int k0 = kt << 5;
    __syncthreads();
    gl16(Ah + aoff + k0,            lw);
    gl16(Ah + aoff + k0 + 64 * 512, lw + 2048);
    gl16(Al + aoff + k0,            lw + 4096);
    gl16(Al + aoff + k0 + 64 * 512, lw + 6144);
    gl16(Bh + boff + k0,            lw + 8192);
    gl16(Bh + boff + k0 + 64 * 512, lw + 10240);
    gl16(Bl + boff + k0,            lw + 12288);
    gl16(Bl + boff + k0 + 64 * 512, lw + 14336);
    __syncthreads();

    bf16x8 aH[4], aL[4], bH[4], bL[4];
#pragma unroll
    for (int mi = 0; mi < 4; ++mi) {
      aH[mi] = *(const bf16x8*)(sm +        (arow + mi * 16) * 32 + kf);
      aL[mi] = *(const bf16x8*)(sm + 4096 + (arow + mi * 16) * 32 + kf);
    }
#pragma unroll
    for (int ni = 0; ni < 4; ++ni) {
      bH[ni] = *(const bf16x8*)(sm + 8192  + (brow + ni * 16) * 32 + kf);
      bL[ni] = *(const bf16x8*)(sm + 12288 + (brow + ni * 16) * 32 + kf);
    }
#pragma unroll
    for (int mi = 0; mi < 4; ++mi)
#pragma unroll
      for (int ni = 0; ni < 4; ++ni) {
        acc[mi][ni] = __builtin_amdgcn_mfma_f32_16x16x32_bf16(aH[mi], bH[ni], acc[mi][ni], 0, 0, 0);
        acc[mi][ni] = __builtin_amdgcn_mfma_f32_16x16x32_bf16(aH[mi], bL[ni], acc[mi][ni], 0, 0, 0);
        acc[mi][ni] = __builtin_amdgcn_mfma_f32_16x16x32_bf16(aL[mi], bH[ni], acc[mi][ni], 0, 0, 0);
      }
  }

  const int erow0 = m0 + ((wv >> 1) << 6) + ((lane >> 4) << 2);
  const int ecol0 = n0 + ((wv & 1) << 6) + (lane & 15);
#pragma unroll
  for (int mi = 0; mi < 4; ++mi)
#pragma unroll
    for (int r = 0; r < 4; ++r) {
      int row = erow0 + mi * 16 + r;
      if (row < G_ROWS) {
#pragma unroll
        for (int ni = 0; ni < 4; ++ni)
          Sim[(size_t)row * T_DIM + ecol0 + ni * 16] = acc[mi][ni][r] * SIM_SCALE;
      }
    }
}

// ---------------- helpers ----------------
__device__ __forceinline__ int count_ge(const float* v, float tau) {
  int c = 0;
#pragma unroll
  for (int j = 0; j < 24; ++j) c += (int)__popcll(__ballot(v[j] >= tau));
  return c;
}
// full 64-lane bitonic sort, descending by u64 key; returns this lane's sorted key
__device__ __forceinline__ u64 bitonic64_desc(u64 key, int lane) {
#pragma unroll
  for (int k = 2; k <= 64; k <<= 1) {
#pragma unroll
    for (int j = k >> 1; j > 0; j >>= 1) {
      u64 p = __shfl_xor(key, j, 64);
      bool lower = (lane & j) == 0;
      bool asc   = (lane & k) != 0;
      u64 mn = (key < p) ? key : p;
      u64 mx = (key < p) ? p : key;
      key = (lower == asc) ? mn : mx;
    }
  }
  return key;
}

// ---------------- per-row (1 wave/row): bisect-select, bitonic rank, np-replica
// at contested boundary, register-direct dense write + scatter ----------------
__global__ __launch_bounds__(256) void topk_kernel(float* __restrict__ Sim, const u32* __restrict__ mbits,
                                                   const float* __restrict__ tg_dec,
                                                   const float* __restrict__ tf_base,
                                                   int* __restrict__ tIdx, float* __restrict__ tW)
{
  __shared__ u32 cval[4][64];
  __shared__ int cidxs[4][64];
  const int lane = threadIdx.x & 63;
  const int wv   = threadIdx.x >> 6;
  const int g    = blockIdx.x * 4 + wv;
  float* row = Sim + (size_t)g * T_DIM;
  const u32* mrow = mbits + (size_t)g * 48;

  // --- load sim (float4) + packed mask nibbles; apply mask -> -inf ---
  float v[24];
#pragma unroll
  for (int j = 0; j < 6; ++j) {
    float4 q = *(const float4*)(row + j * 256 + lane * 4);
    u32 md = mrow[j * 8 + (lane >> 3)];
    u32 nib = (md >> ((lane & 7) * 4)) & 0xFu;
    v[j * 4 + 0] = (nib & 1u) ? q.x : -INFINITY;
    v[j * 4 + 1] = (nib & 2u) ? q.y : -INFINITY;
    v[j * 4 + 2] = (nib & 4u) ? q.z : -INFINITY;
    v[j * 4 + 3] = (nib & 8u) ? q.w : -INFINITY;
  }

  // --- float-space bisect: candidate count in [36, 64] ---
  float tau = -3.0e38f;
  int c_all = count_ge(v, -3.0e38f);
  if (c_all > 64) {
    float lo = -1.f, hi = 4.f;
    bool found = false;
    for (int it = 0; it < 16 && !found; ++it) {
      float mid = 0.5f * (lo + hi);
      int c = count_ge(v, mid);
      if (c > 64)      lo = mid;
      else if (c < 36) hi = mid;
      else { tau = mid; found = true; }
    }
    if (!found) tau = lo;            // prob ~0 (continuous values); compaction clamps
  }

  // --- ballot-prefix compaction into wave-private LDS ---
  int base = 0;
#pragma unroll
  for (int j = 0; j < 24; ++j) {
    bool pred = (v[j] >= tau);
    u64 bmc = __ballot(pred);
    int pos = base + (int)__popcll(bmc & ((1ull << lane) - 1ull));
    int idx = (j >> 2) * 256 + lane * 4 + (j & 3);
    if (pred && pos < 64) { cval[wv][pos] = fkey(v[j]); cidxs[wv][pos] = idx; }
    base += (int)__popcll(bmc);
  }
  const int cnt_eff = (base < 64) ? base : 64;

  u64 key = 0;
  if (lane < cnt_eff)
    key = ((u64)cval[wv][lane] << 32) | (u64)(u32)(~(u32)cidxs[wv][lane]);

  // --- bitonic sort: lane L = L-th largest (value desc, idx asc) ---
  key = bitonic64_desc(key, lane);
  int   myidx = (int)(~(u32)key);
  float myv   = (key != 0) ? funkey((u32)(key >> 32)) : -INFINITY;

  // --- contested boundary? np-replica re-sim only within eps of the 31/32 cut ---
  float v31 = __shfl(myv, 31, 64);
  float v32 = __shfl(myv, 32, 64);
  bool flag = (cnt_eff > TOPK) && (lane < cnt_eff) &&
              (myv >= v32 - BOUND_EPS) && (myv <= v31 + BOUND_EPS);
  if (__ballot(flag) != 0ull) {
    if (flag) {
      // bit-exact np replica: OpenBLAS sgemm sequential-K FMA chain, kc split 384|128,
      // then f32 division by f32(sqrt(512)). Requires strict FP (no fast-math).
      const float* arow_g = tg_dec + (size_t)g * D_DIM;
      const float* brow   = tf_base + (size_t)myidx * D_DIM;
      float s1 = 0.f, s2 = 0.f;
#pragma unroll 8
      for (int k = 0; k < 384; k += 4) {
        float4 av = *(const float4*)(arow_g + k);
        float4 bv = *(const float4*)(brow + k);
        s1 = fmaf(av.x, bv.x, s1); s1 = fmaf(av.y, bv.y, s1);
        s1 = fmaf(av.z, bv.z, s1); s1 = fmaf(av.w, bv.w, s1);
      }
#pragma unroll 8
      for (int k = 384; k < 512; k += 4) {
        float4 av = *(const float4*)(arow_g + k);
        float4 bv = *(const float4*)(brow + k);
        s2 = fmaf(av.x, bv.x, s2); s2 = fmaf(av.y, bv.y, s2);
        s2 = fmaf(av.z, bv.z, s2); s2 = fmaf(av.w, bv.w, s2);
      }
      myv = (s1 + s2) / SQRT_D;
      key = ((u64)fkey(myv) << 32) | (u64)(u32)(~(u32)myidx);
    }
    key = bitonic64_desc(key, lane);
    myidx = (int)(~(u32)key);
    myv   = (key != 0) ? funkey((u32)(key >> 32)) : -INFINITY;
  }

  // --- weights from sorted lanes 0..31 (m-shift cancels; 1e-8*Z dropped: <=1.5e-5 abs) ---
  const bool selme = (lane < TOPK) && (lane < cnt_eff);
  float mx = __shfl(myv, 0, 64);       // top value
  float e = selme ? __expf(myv - mx) : 0.f;
  float E = e;
#pragma unroll
  for (int off = 32; off > 0; off >>= 1) E += __shfl_xor(E, off, 64);
  float rden = (E > 0.f) ? (1.f / E) : 0.f;
  float w = e * rden;

  // --- dense zero write from registers, drain, then sparse scatter ---
  const float4 z4 = make_float4(0.f, 0.f, 0.f, 0.f);
#pragma unroll
  for (int j = 0; j < 6; ++j) *(float4*)(row + j * 256 + lane * 4) = z4;
  asm volatile("s_waitcnt vmcnt(0)" ::: "memory");   // zeros visible before scatter
  if (selme) row[myidx] = w;

  if (cnt_eff < TOPK && lane >= cnt_eff && lane < TOPK) {   // defensive (never for this input)
    tIdx[(size_t)g * TOPK + lane] = 0; tW[(size_t)g * TOPK + lane] = 0.f;
  }
  if (selme) {
    tIdx[(size_t)g * TOPK + lane] = myidx;
    tW[(size_t)g * TOPK + lane]   = w;
  }
}

// ---------------- out0[b,g] = scale * sum_k w[g,k] * tfT[idx[g,k], b] ----------------
__global__ __launch_bounds__(256) void combine_kernel(const float* __restrict__ tfT, const int* __restrict__ tIdx,
                                                      const float* __restrict__ tW, const float* __restrict__ scalep,
                                                      float* __restrict__ out0)
{
  __shared__ int   sIdx[16 * 32];
  __shared__ float sW[16 * 32];
  const int tid = threadIdx.x;
  const int g0 = blockIdx.x * 16;
  for (int i = tid; i < 512; i += 256) {
    sIdx[i] = tIdx[(size_t)g0 * 32 + i];
    sW[i]   = tW[(size_t)g0 * 32 + i];
  }
  __syncthreads();
  const float scale = scalep[0];
  float acc[16];
#pragma unroll
  for (int gi = 0; gi < 16; ++gi) acc[gi] = 0.f;
#pragma unroll 4
  for (int gi = 0; gi < 16; ++gi) {
    float a = 0.f;
#pragma unroll
    for (int k = 0; k < 32; ++k) {
      float w = sW[gi * 32 + k];
      int t   = sIdx[gi * 32 + k];
      a += w * tfT[(size_t)t * B_DIM + tid];
    }
    acc[gi] = a;
  }
  float* dst = out0 + (size_t)tid * G_ROWS + g0;
#pragma unroll
  for (int q = 0; q < 4; ++q) {
    float4 o = make_float4(scale * acc[4*q], scale * acc[4*q+1], scale * acc[4*q+2], scale * acc[4*q+3]);
    *(float4*)(dst + 4 * q) = o;
  }
}

extern "C" void kernel_launch(void* const* d_in, const int* in_sizes, int n_in,
                              void* d_out, int out_size, void* d_ws, size_t ws_size,
                              hipStream_t stream)
{
  const float* tg_dec     = (const float*)d_in[0];
  const float* tf_base    = (const float*)d_in[1];
  const float* tf_expr    = (const float*)d_in[2];
  const int*   motif_mask = (const int*)d_in[3];
  const float* scale      = (const float*)d_in[4];

  float* out0 = (float*)d_out;                           // [B, G]
  float* attn = out0 + (size_t)B_DIM * G_ROWS;           // [G, T] — Sim scratch, overwritten in place

  char* ws = (char*)d_ws;
  u16*   Ah    = (u16*)(ws);                             // G_PAD*512 bf16
  u16*   Al    = (u16*)(ws + 20578304);
  u16*   Bh    = (u16*)(ws + 41156608);                  // 1536*512 bf16
  u16*   Bl    = (u16*)(ws + 42729472);
  float* tfT   = (float*)(ws + 44302336);                // [T, B] f32
  int*   tIdx  = (int*)(ws + 45875200);                  // [G, 32]
  float* tW    = (float*)(ws + 48435200);                // [G, 32]
  u32*   mbits = (u32*)(ws + 50995200);                  // [G, 48] packed mask bits (3.84 MB)

  conv_split<<<10048, 256, 0, stream>>>(tg_dec, Ah, Al, G_ROWS);
  conv_split<<<768,   256, 0, stream>>>(tf_base, Bh, Bl, T_DIM);
  transpose_tf<<<dim3(48, 8), dim3(32, 8), 0, stream>>>(tf_expr, tfT);
  pack_mask<<<5000, 256, 0, stream>>>(motif_mask, mbits);
  gemm_split<<<dim3(12, 157), 256, 0, stream>>>(Ah, Al, Bh, Bl, attn);
  topk_kernel<<<5000, 256, 0, stream>>>(attn, mbits, tg_dec, tf_base, tIdx, tW);
  combine_kernel<<<1250, 256, 0, stream>>>(tfT, tIdx, tW, scale, out0);
}

// Round 8
// 462.092 us; speedup vs baseline: 1.3297x; 1.3297x over previous
//
#include <hip/hip_runtime.h>
#include <cstdint>

typedef unsigned short u16;
typedef unsigned int   u32;
typedef unsigned long long u64;

#define G_ROWS 20000
#define G_PAD  20096      // 157 * 128
#define T_DIM  1536
#define D_DIM  512
#define B_DIM  256
#define TOPK   32
#define SIM_SCALE 0.04419417382415922f   // 1/sqrt(512), screening only
#define SQRT_D    22.62741699796952f     // f32(math.sqrt(512)) — np divides by this
#define BOUND_EPS 2.0e-4f                // per-element screen-vs-np error bound (true ~5e-6; 40x margin)

typedef __bf16 bf16x8 __attribute__((ext_vector_type(8)));
typedef float  f32x4  __attribute__((ext_vector_type(4)));

__device__ __forceinline__ u16 f2bf(float f) {
  u32 u = __float_as_uint(f);
  u += 0x7fffu + ((u >> 16) & 1u);   // RNE
  return (u16)(u >> 16);
}
__device__ __forceinline__ float bf2f(u16 h) {
  return __uint_as_float(((u32)h) << 16);
}
__device__ __forceinline__ u32 fkey(float v) {   // order-preserving f32 -> u32
  u32 b = __float_as_uint(v);
  return (b & 0x80000000u) ? ~b : (b | 0x80000000u);
}
__device__ __forceinline__ float funkey(u32 o) {
  u32 b = (o & 0x80000000u) ? (o & 0x7FFFFFFFu) : ~o;
  return __uint_as_float(b);
}

// ---------------- split-conversion: f32 -> (bf16 hi, bf16 lo) ----------------
__global__ __launch_bounds__(256) void conv_split(const float* __restrict__ src,
                                                  u16* __restrict__ hi, u16* __restrict__ lo,
                                                  int valid_rows)
{
  size_t i = ((size_t)blockIdx.x * 256 + threadIdx.x) * 4;
  int row = (int)(i >> 9);
  float4 a = make_float4(0.f, 0.f, 0.f, 0.f);
  if (row < valid_rows) a = *(const float4*)(src + i);
  float v[4] = {a.x, a.y, a.z, a.w};
  u16 h[4], l[4];
#pragma unroll
  for (int c = 0; c < 4; ++c) {
    h[c] = f2bf(v[c]);
    l[c] = f2bf(v[c] - bf2f(h[c]));
  }
  *(uint2*)(hi + i) = make_uint2((u32)h[0] | ((u32)h[1] << 16), (u32)h[2] | ((u32)h[3] << 16));
  *(uint2*)(lo + i) = make_uint2((u32)l[0] | ((u32)l[1] << 16), (u32)l[2] | ((u32)l[3] << 16));
}

// ---------------- tf_expr [B,T] -> tfT [T,B] ----------------
__global__ __launch_bounds__(256) void transpose_tf(const float* __restrict__ in, float* __restrict__ out)
{
  __shared__ float tile[32][33];
  int x = threadIdx.x, y = threadIdx.y;
  int bt = blockIdx.x * 32;
  int bb = blockIdx.y * 32;
#pragma unroll
  for (int i = 0; i < 32; i += 8) tile[y + i][x] = in[(size_t)(bb + y + i) * T_DIM + bt + x];
  __syncthreads();
#pragma unroll
  for (int i = 0; i < 32; i += 8) out[(size_t)(bt + y + i) * B_DIM + bb + x] = tile[x][y + i];
}

// ---------------- async global -> LDS, 16B/lane ----------------
__device__ __forceinline__ void gl16(const u16* g, u16* l) {
  __builtin_amdgcn_global_load_lds((__attribute__((address_space(1))) void*)(void*)g,
                                   (__attribute__((address_space(3))) void*)l, 16, 0, 0);
}

// ---------------- screening GEMM: C ~= (Ah+Al)(Bh+Bl)^T via 3 bf16 MFMA terms ----------------
__global__ __launch_bounds__(256) void gemm_split(const u16* __restrict__ Ah, const u16* __restrict__ Al,
                                                  const u16* __restrict__ Bh, const u16* __restrict__ Bl,
                                                  float* __restrict__ Sim)
{
  __shared__ u16 sm[16384];
  const int tid  = threadIdx.x;
  const int lane = tid & 63;
  const int wv   = tid >> 6;
  const int m0 = blockIdx.y * 128;
  const int n0 = blockIdx.x * 128;

  f32x4 zero4 = {0.f, 0.f, 0.f, 0.f};
  f32x4 acc[4][4];
#pragma unroll
  for (int i = 0; i < 4; ++i)
#pragma unroll
    for (int j = 0; j < 4; ++j) acc[i][j] = zero4;

  const int r0 = (wv << 4) + (lane >> 2);
  const int c0 = (lane & 3) << 3;
  const size_t aoff = (size_t)(m0 + r0) * 512 + c0;
  const size_t boff = (size_t)(n0 + r0) * 512 + c0;
  u16* lw = sm + (wv << 9);

  const int arow = ((wv >> 1) << 6) + (lane & 15);
  const int brow = ((wv & 1) << 6) + (lane & 15);
  const int kf   = (lane >> 4) << 3;

  for (int kt = 0; kt < 16; ++kt) {
    const int k0 = kt << 5;
    __syncthreads();
    gl16(Ah + aoff + k0,            lw);
    gl16(Ah + aoff + k0 + 64 * 512, lw + 2048);
    gl16(Al + aoff + k0,            lw + 4096);
    gl16(Al + aoff + k0 + 64 * 512, lw + 6144);
    gl16(Bh + boff + k0,            lw + 8192);
    gl16(Bh + boff + k0 + 64 * 512, lw + 10240);
    gl16(Bl + boff + k0,            lw + 12288);
    gl16(Bl + boff + k0 + 64 * 512, lw + 14336);
    __syncthreads();

    bf16x8 aH[4], aL[4], bH[4], bL[4];
#pragma unroll
    for (int mi = 0; mi < 4; ++mi) {
      aH[mi] = *(const bf16x8*)(sm +        (arow + mi * 16) * 32 + kf);
      aL[mi] = *(const bf16x8*)(sm + 4096 + (arow + mi * 16) * 32 + kf);
    }
#pragma unroll
    for (int ni = 0; ni < 4; ++ni) {
      bH[ni] = *(const bf16x8*)(sm + 8192  + (brow + ni * 16) * 32 + kf);
      bL[ni] = *(const bf16x8*)(sm + 12288 + (brow + ni * 16) * 32 + kf);
    }
#pragma unroll
    for (int mi = 0; mi < 4; ++mi)
#pragma unroll
      for (int ni = 0; ni < 4; ++ni) {
        acc[mi][ni] = __builtin_amdgcn_mfma_f32_16x16x32_bf16(aH[mi], bH[ni], acc[mi][ni], 0, 0, 0);
        acc[mi][ni] = __builtin_amdgcn_mfma_f32_16x16x32_bf16(aH[mi], bL[ni], acc[mi][ni], 0, 0, 0);
        acc[mi][ni] = __builtin_amdgcn_mfma_f32_16x16x32_bf16(aL[mi], bH[ni], acc[mi][ni], 0, 0, 0);
      }
  }

  const int erow0 = m0 + ((wv >> 1) << 6) + ((lane >> 4) << 2);
  const int ecol0 = n0 + ((wv & 1) << 6) + (lane & 15);
#pragma unroll
  for (int mi = 0; mi < 4; ++mi)
#pragma unroll
    for (int r = 0; r < 4; ++r) {
      int row = erow0 + mi * 16 + r;
      if (row < G_ROWS) {
#pragma unroll
        for (int ni = 0; ni < 4; ++ni)
          Sim[(size_t)row * T_DIM + ecol0 + ni * 16] = acc[mi][ni][r] * SIM_SCALE;
      }
    }
}

// ---------------- helpers ----------------
__device__ __forceinline__ int count_ge(const float* v, float tau) {
  int c = 0;
#pragma unroll
  for (int j = 0; j < 24; ++j) c += (int)__popcll(__ballot(v[j] >= tau));
  return c;
}
// full 64-lane bitonic sort, descending by u64 key; returns this lane's sorted key
__device__ __forceinline__ u64 bitonic64_desc(u64 key, int lane) {
#pragma unroll
  for (int k = 2; k <= 64; k <<= 1) {
#pragma unroll
    for (int j = k >> 1; j > 0; j >>= 1) {
      u64 p = __shfl_xor(key, j, 64);
      bool lower = (lane & j) == 0;
      bool asc   = (lane & k) != 0;
      u64 mn = (key < p) ? key : p;
      u64 mx = (key < p) ? p : key;
      key = (lower == asc) ? mn : mx;
    }
  }
  return key;
}

// ---------------- per-row (1 wave/row): 6-threshold ladder select, bitonic rank,
// np-replica ONLY when cut is truly contested, register-direct dense write ----------------
__global__ __launch_bounds__(256) void topk_kernel(float* __restrict__ Sim, const int* __restrict__ mask,
                                                   const float* __restrict__ tg_dec,
                                                   const float* __restrict__ tf_base,
                                                   int* __restrict__ tIdx, float* __restrict__ tW)
{
  __shared__ u32 cval[4][64];
  __shared__ int cidxs[4][64];
  const int lane = threadIdx.x & 63;
  const int wv   = threadIdx.x >> 6;
  const int g    = blockIdx.x * 4 + wv;
  float* row = Sim + (size_t)g * T_DIM;
  const int* mrow = mask + (size_t)g * T_DIM;

  // --- vectorized load of sim + mask; apply mask -> -inf ---
  float v[24];
#pragma unroll
  for (int j = 0; j < 6; ++j) {
    float4 q = *(const float4*)(row + j * 256 + lane * 4);
    int4  mq = *(const int4*)(mrow + j * 256 + lane * 4);
    v[j * 4 + 0] = mq.x ? q.x : -INFINITY;
    v[j * 4 + 1] = mq.y ? q.y : -INFINITY;
    v[j * 4 + 2] = mq.z ? q.z : -INFINITY;
    v[j * 4 + 3] = mq.w ? q.w : -INFINITY;
  }

  // --- parallel 6-threshold ladder count (pure VALU) + valid count ---
  const float TH0 = 1.25f, TH1 = 1.40f, TH2 = 1.55f, TH3 = 1.70f, TH4 = 1.85f, TH5 = 2.00f;
  int n0 = 0, n1 = 0, n2 = 0, n3 = 0, n4 = 0, n5 = 0, nv = 0;
#pragma unroll
  for (int j = 0; j < 24; ++j) {
    float x = v[j];
    n0 += (x >= TH0); n1 += (x >= TH1); n2 += (x >= TH2);
    n3 += (x >= TH3); n4 += (x >= TH4); n5 += (x >= TH5);
    nv += (x != -INFINITY);
  }
  // pack 16-bit fields into two u64s, one shfl-reduce pass
  u64 p0 = (u64)(u32)n0 | ((u64)(u32)n1 << 16) | ((u64)(u32)n2 << 32) | ((u64)(u32)n3 << 48);
  u64 p1 = (u64)(u32)n4 | ((u64)(u32)n5 << 16) | ((u64)(u32)nv << 32);
#pragma unroll
  for (int off = 32; off > 0; off >>= 1) {
    p0 += __shfl_xor(p0, off, 64);
    p1 += __shfl_xor(p1, off, 64);
  }
  int c[6];
  c[0] = (int)(p0 & 0xFFFF); c[1] = (int)((p0 >> 16) & 0xFFFF);
  c[2] = (int)((p0 >> 32) & 0xFFFF); c[3] = (int)((p0 >> 48) & 0xFFFF);
  c[4] = (int)(p1 & 0xFFFF); c[5] = (int)((p1 >> 16) & 0xFFFF);
  const int cvalid = (int)((p1 >> 32) & 0xFFFF);

  // --- pick largest threshold with count >= 33; fallback bisect for gaps/extremes (~1%) ---
  float tau; int cnt;
  if (cvalid <= 64) { tau = -3.0e38f; cnt = cvalid; }
  else {
    int is = -1;
#pragma unroll
    for (int i = 0; i < 6; ++i) if (c[i] >= 33) is = i;
    const float THv[7] = {TH0, TH1, TH2, TH3, TH4, TH5, 8.0f};
    if (is >= 0 && c[is] <= 64) { tau = THv[is]; cnt = c[is]; }
    else {
      float lo, hi;
      if (is < 0) { lo = -4.0f; hi = TH0; }         // even TH0 keeps <33 (tiny-scale row)
      else        { lo = THv[is]; hi = THv[is + 1]; } // gap: count(lo)>64, count(hi)<33
      tau = lo; cnt = 1000;
      for (int it = 0; it < 16; ++it) {
        float mid = 0.5f * (lo + hi);
        int cm = count_ge(v, mid);
        if (cm > 64)      lo = mid;
        else if (cm < 33) hi = mid;
        else { tau = mid; cnt = cm; break; }
      }
      if (cnt == 1000) tau = lo;                    // exact-tie pathology; compaction clamps
    }
  }

  // --- ballot-prefix compaction into wave-private LDS ---
  int base = 0;
#pragma unroll
  for (int j = 0; j < 24; ++j) {
    bool pred = (v[j] >= tau);
    u64 bmc = __ballot(pred);
    int pos = base + (int)__popcll(bmc & ((1ull << lane) - 1ull));
    int idx = (j >> 2) * 256 + lane * 4 + (j & 3);
    if (pred && pos < 64) { cval[wv][pos] = fkey(v[j]); cidxs[wv][pos] = idx; }
    base += (int)__popcll(bmc);
  }
  const int cnt_eff = (base < 64) ? base : 64;

  u64 key = 0;
  if (lane < cnt_eff)
    key = ((u64)cval[wv][lane] << 32) | (u64)(u32)(~(u32)cidxs[wv][lane]);

  // --- bitonic sort: lane L = L-th largest (value desc, idx asc) ---
  key = bitonic64_desc(key, lane);
  int   myidx = (int)(~(u32)key);
  float myv   = (key != 0) ? funkey((u32)(key >> 32)) : -INFINITY;

  // --- np-replica ONLY if the 31/32 cut is truly contested: v31 - v32 < 2*eps ---
  float v31 = __shfl(myv, 31, 64);
  float v32 = __shfl(myv, 32, 64);
  if (cnt_eff > TOPK && (v31 - v32) < 2.0f * BOUND_EPS) {
    bool flag = (lane < cnt_eff) &&
                (myv >= v32 - 2.0f * BOUND_EPS) && (myv <= v31 + 2.0f * BOUND_EPS);
    if (flag) {
      // bit-exact np replica: OpenBLAS sgemm sequential-K FMA chain, kc split 384|128,
      // then f32 division by f32(sqrt(512)). Requires strict FP (no fast-math).
      const float* arow_g = tg_dec + (size_t)g * D_DIM;
      const float* brow   = tf_base + (size_t)myidx * D_DIM;
      float s1 = 0.f, s2 = 0.f;
#pragma unroll 8
      for (int k = 0; k < 384; k += 4) {
        float4 av = *(const float4*)(arow_g + k);
        float4 bv = *(const float4*)(brow + k);
        s1 = fmaf(av.x, bv.x, s1); s1 = fmaf(av.y, bv.y, s1);
        s1 = fmaf(av.z, bv.z, s1); s1 = fmaf(av.w, bv.w, s1);
      }
#pragma unroll 8
      for (int k = 384; k < 512; k += 4) {
        float4 av = *(const float4*)(arow_g + k);
        float4 bv = *(const float4*)(brow + k);
        s2 = fmaf(av.x, bv.x, s2); s2 = fmaf(av.y, bv.y, s2);
        s2 = fmaf(av.z, bv.z, s2); s2 = fmaf(av.w, bv.w, s2);
      }
      myv = (s1 + s2) / SQRT_D;
      key = ((u64)fkey(myv) << 32) | (u64)(u32)(~(u32)myidx);
    }
    key = bitonic64_desc(key, lane);
    myidx = (int)(~(u32)key);
    myv   = (key != 0) ? funkey((u32)(key >> 32)) : -INFINITY;
  }

  // --- weights from sorted lanes 0..31 (m-shift cancels; 1e-8*Z dropped: <=1.5e-5 abs) ---
  const bool selme = (lane < TOPK) && (lane < cnt_eff);
  float mx = __shfl(myv, 0, 64);       // top value
  float e = selme ? __expf(myv - mx) : 0.f;
  float E = e;
#pragma unroll
  for (int off = 32; off > 0; off >>= 1) E += __shfl_xor(E, off, 64);
  float rden = (E > 0.f) ? (1.f / E) : 0.f;
  float w = e * rden;

  // --- dense zero write from registers, drain, then sparse scatter ---
  const float4 z4 = make_float4(0.f, 0.f, 0.f, 0.f);
#pragma unroll
  for (int j = 0; j < 6; ++j) *(float4*)(row + j * 256 + lane * 4) = z4;
  asm volatile("s_waitcnt vmcnt(0)" ::: "memory");   // zeros visible before scatter
  if (selme) row[myidx] = w;

  if (cnt_eff < TOPK && lane >= cnt_eff && lane < TOPK) {   // defensive (never for this input)
    tIdx[(size_t)g * TOPK + lane] = 0; tW[(size_t)g * TOPK + lane] = 0.f;
  }
  if (selme) {
    tIdx[(size_t)g * TOPK + lane] = myidx;
    tW[(size_t)g * TOPK + lane]   = w;
  }
}

// ---------------- out0[b,g] = scale * sum_k w[g,k] * tfT[idx[g,k], b] ----------------
__global__ __launch_bounds__(256) void combine_kernel(const float* __restrict__ tfT, const int* __restrict__ tIdx,
                                                      const float* __restrict__ tW, const float* __restrict__ scalep,
                                                      float* __restrict__ out0)
{
  __shared__ int   sIdx[16 * 32];
  __shared__ float sW[16 * 32];
  const int tid = threadIdx.x;
  const int g0 = blockIdx.x * 16;
  for (int i = tid; i < 512; i += 256) {
    sIdx[i] = tIdx[(size_t)g0 * 32 + i];
    sW[i]   = tW[(size_t)g0 * 32 + i];
  }
  __syncthreads();
  const float scale = scalep[0];
  float acc[16];
#pragma unroll
  for (int gi = 0; gi < 16; ++gi) acc[gi] = 0.f;
#pragma unroll 4
  for (int gi = 0; gi < 16; ++gi) {
    float a = 0.f;
#pragma unroll
    for (int k = 0; k < 32; ++k) {
      float w = sW[gi * 32 + k];
      int t   = sIdx[gi * 32 + k];
      a += w * tfT[(size_t)t * B_DIM + tid];
    }
    acc[gi] = a;
  }
  float* dst = out0 + (size_t)tid * G_ROWS + g0;
#pragma unroll
  for (int q = 0; q < 4; ++q) {
    float4 o = make_float4(scale * acc[4*q], scale * acc[4*q+1], scale * acc[4*q+2], scale * acc[4*q+3]);
    *(float4*)(dst + 4 * q) = o;
  }
}

extern "C" void kernel_launch(void* const* d_in, const int* in_sizes, int n_in,
                              void* d_out, int out_size, void* d_ws, size_t ws_size,
                              hipStream_t stream)
{
  const float* tg_dec     = (const float*)d_in[0];
  const float* tf_base    = (const float*)d_in[1];
  const float* tf_expr    = (const float*)d_in[2];
  const int*   motif_mask = (const int*)d_in[3];
  const float* scale      = (const float*)d_in[4];

  float* out0 = (float*)d_out;                           // [B, G]
  float* attn = out0 + (size_t)B_DIM * G_ROWS;           // [G, T] — Sim scratch, overwritten in place

  char* ws = (char*)d_ws;
  u16*   Ah    = (u16*)(ws);                             // G_PAD*512 bf16
  u16*   Al    = (u16*)(ws + 20578304);
  u16*   Bh    = (u16*)(ws + 41156608);                  // 1536*512 bf16
  u16*   Bl    = (u16*)(ws + 42729472);
  float* tfT   = (float*)(ws + 44302336);                // [T, B] f32
  int*   tIdx  = (int*)(ws + 45875200);                  // [G, 32]
  float* tW    = (float*)(ws + 48435200);                // [G, 32]

  conv_split<<<10048, 256, 0, stream>>>(tg_dec, Ah, Al, G_ROWS);
  conv_split<<<768,   256, 0, stream>>>(tf_base, Bh, Bl, T_DIM);
  transpose_tf<<<dim3(48, 8), dim3(32, 8), 0, stream>>>(tf_expr, tfT);
  gemm_split<<<dim3(12, 157), 256, 0, stream>>>(Ah, Al, Bh, Bl, attn);
  topk_kernel<<<5000, 256, 0, stream>>>(attn, motif_mask, tg_dec, tf_base, tIdx, tW);
  combine_kernel<<<1250, 256, 0, stream>>>(tfT, tIdx, tW, scale, out0);
}